// Round 1
// 525.562 us; speedup vs baseline: 1.0631x; 1.0631x over previous
//
#include <hip/hip_runtime.h>
#include <math.h>

#define T_STEPS 512
#define NF 4
#define HID 32
#define BN_EPS 1e-5f
#define LOG2E 1.44269504088896340736f

typedef float    f32x4 __attribute__((ext_vector_type(4)));
typedef _Float16 f16x2 __attribute__((ext_vector_type(2)));
typedef _Float16 f16x8 __attribute__((ext_vector_type(8)));

struct F8 { f16x2 p[4]; };

__device__ __forceinline__ f16x2 pk16(float x, float y) {
  return __builtin_bit_cast(f16x2, __builtin_amdgcn_cvt_pkrtz(x, y));
}
__device__ __forceinline__ f16x8 mk8(f16x2 a, f16x2 b, f16x2 c, f16x2 d) {
  F8 f; f.p[0] = a; f.p[1] = b; f.p[2] = c; f.p[3] = d;
  return __builtin_bit_cast(f16x8, f);
}
#if __has_builtin(__builtin_amdgcn_exp2f)
__device__ __forceinline__ float ex2(float x) { return __builtin_amdgcn_exp2f(x); }
#else
__device__ __forceinline__ float ex2(float x) { return exp2f(x); }
#endif
__device__ __forceinline__ float fsigmoid(float x) {
  return __builtin_amdgcn_rcpf(1.0f + __expf(-x));   // validated r1..r8
}
__device__ __forceinline__ f32x4 mfma16(f16x8 a, f16x8 b, f32x4 c) {
  return __builtin_amdgcn_mfma_f32_16x16x32_f16(a, b, c, 0, 0, 0);
}

// r9: 8 waves per 16-row tile, ONE gate D-tile per wave (tile g == wave id).
// Grid stays 512 -> 2 blocks/CU but 4 waves/SIMD (was 2): 2x latency hiding.
// c/h update is now SPLIT across waves (wave w owns hidden [4w,4w+4), 1 elem
// per lane -> 2 trans) instead of 4x-redundant (16 trans): per-SIMD trans
// issue per step drops 68 -> 48 while resident waves double.
// Exchange: activated gates via sact (barrier 1), h via sh (barrier 2).
// Single-buffered LDS is race-free: all sact reads complete before barrier 2,
// all sh reads are in-register before any wave passes barrier 1 of step t+1.
// Gate pre-activations pre-scaled by ke = -log2e (-2log2e for g) so
// activation = aA*rcp(1+exp2(D)) + bA. d stays OUT of the MFMA operands:
// W1*h rides Bh, wd*d is a VALU post-add (d-reduce runs in the MFMA shadow).
__global__ __launch_bounds__(512, 4) void hedge_kernel(
    const float* __restrict__ x,
    const float* __restrict__ bn_g, const float* __restrict__ bn_b,
    const float* __restrict__ bn_m, const float* __restrict__ bn_v,
    const float* __restrict__ W_ih, const float* __restrict__ b_ih,
    const float* __restrict__ W_hh, const float* __restrict__ b_hh,
    const float* __restrict__ W1,   const float* __restrict__ b1,
    const float* __restrict__ W2,   const float* __restrict__ b2,
    float* __restrict__ out)
{
  // [gate-tile g][q][n] of f32x4: writes b128, reads b32 (2-way alias = free)
  __shared__ f32x4 sact[8][4][16];                  // 8 KB
  __shared__ __align__(16) float sh[16][36];        // [n][hid], +4 pad, 2.25 KB

  const int tid  = threadIdx.x;
  const int lane = tid & 63;
  const int w    = tid >> 6;           // wave id == gate-tile id, [0,8)
  const int n    = lane & 15;          // batch column
  const int q    = lane >> 4;          // quad
  const int row  = blockIdx.x * 16 + n;
  const int gate = w >> 1;             // 0:i 1:f 2:g 3:o

  // ---- fold BatchNorm (z*scale + shift) into weights and bias
  float scale[5], shift[5];
  #pragma unroll
  for (int f = 0; f < 5; ++f) {
    float s = bn_g[f] * rsqrtf(bn_v[f] + BN_EPS);
    scale[f] = s;
    shift[f] = fmaf(-bn_m[f], s, bn_b[f]);
  }

  const float ke = (gate == 2) ? -2.0f * LOG2E : -LOG2E;
  const float aA = (gate == 2) ?  2.0f : 1.0f;
  const float bA = (gate == 2) ? -1.0f : 0.0f;

  const f16x2 zz = {(_Float16)0, (_Float16)0};

  // A/B layouts + K-permutation identical to r8 (verified):
  //   A: m=lane&15, k-slot j -> pi(8q+j) = (j<4) ? 4q+j : 16+4q+(j-4)
  //   D: n=lane&15, m=4q+reg
  f16x8 Ahh, Aih;
  f32x4 Cb, Wd;
  {
    const float* Wr = &W_hh[(16 * w + n) * HID];
    const f32x4 lo = *(const f32x4*)&Wr[4 * q];
    const f32x4 hi = *(const f32x4*)&Wr[16 + 4 * q];
    Ahh = mk8(pk16(ke * lo.x, ke * lo.y), pk16(ke * lo.z, ke * lo.w),
              pk16(ke * hi.x, ke * hi.y), pk16(ke * hi.z, ke * hi.w));
    const float* Wi = &W_ih[(16 * w + n) * 5];
    Aih = mk8(q == 0 ? pk16(ke * Wi[0] * scale[0], ke * Wi[1] * scale[1]) : zz,
              q == 0 ? pk16(ke * Wi[2] * scale[2], ke * Wi[3] * scale[3]) : zz,
              zz, zz);
    #pragma unroll
    for (int r2 = 0; r2 < 4; ++r2) {
      const int rr = 16 * w + 4 * q + r2;
      float a = b_ih[rr] + b_hh[rr];
      #pragma unroll
      for (int f = 0; f < 5; ++f) a = fmaf(W_ih[rr * 5 + f], shift[f], a);
      Cb[r2] = ke * a;
      Wd[r2] = ke * W_ih[rr * 5 + 4] * scale[4];
    }
  }
  // MLP fragments (unscaled), redundant in every wave (keeps d local)
  f16x8 Aw1[2];
  f32x4 Cb1[2], W2v[2];
  #pragma unroll
  for (int p = 0; p < 2; ++p) {
    const float* Wr = &W1[(16 * p + n) * HID];
    const f32x4 lo = *(const f32x4*)&Wr[4 * q];
    const f32x4 hi = *(const f32x4*)&Wr[16 + 4 * q];
    Aw1[p] = mk8(pk16(lo.x, lo.y), pk16(lo.z, lo.w),
                 pk16(hi.x, hi.y), pk16(hi.z, hi.w));
    #pragma unroll
    for (int r2 = 0; r2 < 4; ++r2) {
      Cb1[p][r2] = b1[16 * p + 4 * q + r2];
      W2v[p][r2] = W2[16 * p + 4 * q + r2];
    }
  }
  const float b2s = b2[0];

  // ---- c/h ownership: this lane updates (hid = 4w + q, batch = n).
  // Gate row r for hid: i=hid f=32+hid g=64+hid o=96+hid; element offsets in
  // flat sact floats: tile stride = 256 floats -> +512/+1024/+1536.
  const float* sA   = (const float*)sact;
  const int ibase   = (((w >> 2) * 4 + (w & 3)) * 16 + n) * 4 + q;
  const int hwrite  = 4 * w + q;       // hid this lane writes into sh[n][.]

  const float* xrow = x + (size_t)row * (T_STEPS * NF);
  float*       orow = out + (size_t)row * T_STEPS;

  float ccur = 0.0f;                   // single c element per lane now
  f16x8 Bh = mk8(zz, zz, zz, zz);      // h_{-1} = 0
  f32x4 xv = *(const f32x4*)xrow;      // x_0

  #pragma unroll 1
  for (int t = 0; t < T_STEPS; ++t) {
    const int tn = (t + 1 < T_STEPS) ? t + 1 : t;
    const f32x4 xn = *(const f32x4*)(xrow + tn * NF);   // prefetch x_{t+1}

    // ---- MFMA block: gate tile w from h_{t-1},x_t AND MLP(h_{t-1}) -> d_{t-1}
    const f16x8 Bz = mk8(q == 0 ? pk16(xv.x, xv.y) : zz,
                         q == 0 ? pk16(xv.z, xv.w) : zz, zz, zz);
    f32x4 D = mfma16(Aih, Bz, mfma16(Ahh, Bh, Cb));
    const f32x4 M0 = mfma16(Aw1[0], Bh, Cb1[0]);
    const f32x4 M1 = mfma16(Aw1[1], Bh, Cb1[1]);

    // ---- d_{t-1} = sigmoid(relu(M)*W2 + b2)  (off critical path of D)
    float y = 0.0f;
    #pragma unroll
    for (int r2 = 0; r2 < 4; ++r2) {
      y = fmaf(W2v[0][r2], fmaxf(M0[r2], 0.0f), y);
      y = fmaf(W2v[1][r2], fmaxf(M1[r2], 0.0f), y);
    }
    y += __builtin_bit_cast(float, __builtin_amdgcn_ds_swizzle(
             __builtin_bit_cast(int, y), 0x401F));      // xor-16 (q^1)
    y += __shfl_xor(y, 32);                             // q^2
    float dl = fsigmoid(y + b2s);
    dl = t ? dl : 0.0f;                                 // reference d_{-1} = 0
    if (w == 0 && q == 0 && t) orow[t - 1] = dl;

    // ---- d-term post-add (Wd is ke-scaled like D), then activation
    f32x4 A;
    #pragma unroll
    for (int r2 = 0; r2 < 4; ++r2) {
      const float dd = fmaf(Wd[r2], dl, D[r2]);
      A[r2] = fmaf(aA, __builtin_amdgcn_rcpf(1.0f + ex2(dd)), bA);
    }

    // ---- exchange activated gates (barrier 1)
    sact[w][q][n] = A;
    __syncthreads();

    // ---- c/h update for OWN (hid, n) slice: 1 element, 2 trans ops
    const float iv = sA[ibase];
    const float fv = sA[ibase + 512];
    const float gv = sA[ibase + 1024];
    const float ov = sA[ibase + 1536];
    const float cc = fmaf(fv, ccur, iv * gv);
    ccur = cc;
    const float tc = fmaf(2.0f,
        __builtin_amdgcn_rcpf(1.0f + ex2(-2.0f * LOG2E * cc)), -1.0f);
    sh[n][hwrite] = ov * tc;

    // ---- exchange h (barrier 2), repack Bh for next step
    __syncthreads();
    const f32x4 hlo = *(const f32x4*)&sh[n][4 * q];
    const f32x4 hhi = *(const f32x4*)&sh[n][16 + 4 * q];
    Bh = mk8(pk16(hlo.x, hlo.y), pk16(hlo.z, hlo.w),
             pk16(hhi.x, hhi.y), pk16(hhi.z, hhi.w));
    xv = xn;
  }

  // ---- epilogue: d_{T-1} from h_{T-1}
  const f32x4 M0 = mfma16(Aw1[0], Bh, Cb1[0]);
  const f32x4 M1 = mfma16(Aw1[1], Bh, Cb1[1]);
  float y = 0.0f;
  #pragma unroll
  for (int r2 = 0; r2 < 4; ++r2) {
    y = fmaf(W2v[0][r2], fmaxf(M0[r2], 0.0f), y);
    y = fmaf(W2v[1][r2], fmaxf(M1[r2], 0.0f), y);
  }
  y += __builtin_bit_cast(float, __builtin_amdgcn_ds_swizzle(
           __builtin_bit_cast(int, y), 0x401F));
  y += __shfl_xor(y, 32);
  const float dl = fsigmoid(y + b2s);
  if (w == 0 && q == 0) orow[T_STEPS - 1] = dl;
}

extern "C" void kernel_launch(void* const* d_in, const int* in_sizes, int n_in,
                              void* d_out, int out_size, void* d_ws, size_t ws_size,
                              hipStream_t stream) {
  const float* x    = (const float*)d_in[0];
  const float* bn_g = (const float*)d_in[1];
  const float* bn_b = (const float*)d_in[2];
  const float* bn_m = (const float*)d_in[3];
  const float* bn_v = (const float*)d_in[4];
  const float* W_ih = (const float*)d_in[5];
  const float* b_ih = (const float*)d_in[6];
  const float* W_hh = (const float*)d_in[7];
  const float* b_hh = (const float*)d_in[8];
  const float* W1   = (const float*)d_in[9];
  const float* b1   = (const float*)d_in[10];
  const float* W2   = (const float*)d_in[11];
  const float* b2   = (const float*)d_in[12];
  float* out = (float*)d_out;

  const int B = in_sizes[0] / (T_STEPS * NF);   // 8192
  const int grid = B / 16;                      // 16 rows per 8-wave block -> 512

  hipLaunchKernelGGL(hedge_kernel, dim3(grid), dim3(512), 0, stream,
                     x, bn_g, bn_b, bn_m, bn_v, W_ih, b_ih, W_hh, b_hh,
                     W1, b1, W2, b2, out);
}

// Round 2
// 519.257 us; speedup vs baseline: 1.0760x; 1.0121x over previous
//
#include <hip/hip_runtime.h>
#include <math.h>

#define T_STEPS 512
#define NF 4
#define HID 32
#define BN_EPS 1e-5f
#define LOG2E 1.44269504088896340736f

typedef float    f32x4 __attribute__((ext_vector_type(4)));
typedef _Float16 f16x2 __attribute__((ext_vector_type(2)));
typedef _Float16 f16x8 __attribute__((ext_vector_type(8)));

struct F8 { f16x2 p[4]; };

__device__ __forceinline__ f16x2 pk16(float x, float y) {
  return __builtin_bit_cast(f16x2, __builtin_amdgcn_cvt_pkrtz(x, y));
}
__device__ __forceinline__ f16x8 mk8(f16x2 a, f16x2 b, f16x2 c, f16x2 d) {
  F8 f; f.p[0] = a; f.p[1] = b; f.p[2] = c; f.p[3] = d;
  return __builtin_bit_cast(f16x8, f);
}
#if __has_builtin(__builtin_amdgcn_exp2f)
__device__ __forceinline__ float ex2(float x) { return __builtin_amdgcn_exp2f(x); }
#else
__device__ __forceinline__ float ex2(float x) { return exp2f(x); }
#endif
__device__ __forceinline__ float fsigmoid(float x) {
  return __builtin_amdgcn_rcpf(1.0f + __expf(-x));   // validated r1..r8
}
__device__ __forceinline__ f32x4 mfma16(f16x8 a, f16x8 b, f32x4 c) {
  return __builtin_amdgcn_mfma_f32_16x16x32_f16(a, b, c, 0, 0, 0);
}

// r10: ONE wave per 16-batch job, ZERO barriers, ZERO LDS.
// r9 post-mortem: dur invariant under 2x occupancy + halved trans work, and
// new 3.8e7 bank-conflict cycles -> the barrier-serialized LDS round-trip
// chain IS the step time. This version removes the exchange entirely:
//  - D layout (n=lane&15, m=4q+reg) means i,f,g,o for a (hid,n) pair live in
//    the SAME lane across the 8 gate D-tiles -> c/h update is lane-local.
//  - The h values a lane then owns (hid in {4q+r} u {16+4q+r}) are exactly
//    the k-slots pi(8q+j) of its OWN Bh B-fragment -> repack is lane-local.
// Per wave-step: 18 mfma + ~64 trans + ~70 VALU, all in-register; the only
// cross-lane op left is the d-reduce (ds_swizzle + shfl, intra-wave).
// 512 independent waves (~1/SIMD): recurrence-limited, latency hidden by ILP
// across the 8 independent gate tiles.
// Gate pre-activations pre-scaled by keT = -log2e (-2log2e for g, tiles 4/5)
// inside weights/bias so activation = rcp(1+exp2(D)) (g: 2*rcp-1).
__global__ __launch_bounds__(64, 1) void hedge_kernel(
    const float* __restrict__ x,
    const float* __restrict__ bn_g, const float* __restrict__ bn_b,
    const float* __restrict__ bn_m, const float* __restrict__ bn_v,
    const float* __restrict__ W_ih, const float* __restrict__ b_ih,
    const float* __restrict__ W_hh, const float* __restrict__ b_hh,
    const float* __restrict__ W1,   const float* __restrict__ b1,
    const float* __restrict__ W2,   const float* __restrict__ b2,
    float* __restrict__ out)
{
  const int lane = threadIdx.x & 63;
  const int n    = lane & 15;          // batch column (and A-fragment row m)
  const int q    = lane >> 4;          // quad
  const int row  = blockIdx.x * 16 + n;

  // ---- fold BatchNorm (z*scale + shift) into weights and bias
  float scale[5], shift[5];
  #pragma unroll
  for (int f = 0; f < 5; ++f) {
    float s = bn_g[f] * rsqrtf(bn_v[f] + BN_EPS);
    scale[f] = s;
    shift[f] = fmaf(-bn_m[f], s, bn_b[f]);
  }

  const f16x2 zz = {(_Float16)0, (_Float16)0};

  // A/B layouts + K-permutation identical to r8/r9 (verified):
  //   A: m=lane&15, k-slot j -> pi(8q+j) = (j<4) ? 4q+j : 16+4q+(j-4)
  //   D: n=lane&15, m=4q+reg
  // Tile t covers gate-rows [16t, 16t+16): i=tiles 0,1  f=2,3  g=4,5  o=6,7.
  f16x8 Ahh[8], Aih[8];
  f32x4 Cb[8], Wd[8];
  #pragma unroll
  for (int tl = 0; tl < 8; ++tl) {
    const float ke = (tl == 4 || tl == 5) ? -2.0f * LOG2E : -LOG2E;
    const float* Wr = &W_hh[(16 * tl + n) * HID];
    const f32x4 lo = *(const f32x4*)&Wr[4 * q];
    const f32x4 hi = *(const f32x4*)&Wr[16 + 4 * q];
    Ahh[tl] = mk8(pk16(ke * lo.x, ke * lo.y), pk16(ke * lo.z, ke * lo.w),
                  pk16(ke * hi.x, ke * hi.y), pk16(ke * hi.z, ke * hi.w));
    const float* Wi = &W_ih[(16 * tl + n) * 5];
    Aih[tl] = mk8(q == 0 ? pk16(ke * Wi[0] * scale[0], ke * Wi[1] * scale[1]) : zz,
                  q == 0 ? pk16(ke * Wi[2] * scale[2], ke * Wi[3] * scale[3]) : zz,
                  zz, zz);
    #pragma unroll
    for (int r2 = 0; r2 < 4; ++r2) {
      const int rr = 16 * tl + 4 * q + r2;
      float a = b_ih[rr] + b_hh[rr];
      #pragma unroll
      for (int f = 0; f < 5; ++f) a = fmaf(W_ih[rr * 5 + f], shift[f], a);
      Cb[tl][r2] = ke * a;
      Wd[tl][r2] = ke * W_ih[rr * 5 + 4] * scale[4];
    }
  }
  // MLP fragments (unscaled)
  f16x8 Aw1[2];
  f32x4 Cb1[2], W2v[2];
  #pragma unroll
  for (int p = 0; p < 2; ++p) {
    const float* Wr = &W1[(16 * p + n) * HID];
    const f32x4 lo = *(const f32x4*)&Wr[4 * q];
    const f32x4 hi = *(const f32x4*)&Wr[16 + 4 * q];
    Aw1[p] = mk8(pk16(lo.x, lo.y), pk16(lo.z, lo.w),
                 pk16(hi.x, hi.y), pk16(hi.z, hi.w));
    #pragma unroll
    for (int r2 = 0; r2 < 4; ++r2) {
      Cb1[p][r2] = b1[16 * p + 4 * q + r2];
      W2v[p][r2] = W2[16 * p + 4 * q + r2];
    }
  }
  const float b2s = b2[0];

  const float* xrow = x + (size_t)row * (T_STEPS * NF);
  float*       orow = out + (size_t)row * T_STEPS;

  // lane-local recurrent state: c for hid = 4q+s (s<4) and 16+4q+(s-4) (s>=4)
  float cst[8] = {0, 0, 0, 0, 0, 0, 0, 0};
  f16x8 Bh = mk8(zz, zz, zz, zz);          // h_{-1} = 0
  f32x4 xv = *(const f32x4*)xrow;          // x_0

  #pragma unroll 1
  for (int t = 0; t < T_STEPS; ++t) {
    const int tn = (t + 1 < T_STEPS) ? t + 1 : t;
    const f32x4 xn = *(const f32x4*)(xrow + tn * NF);   // prefetch x_{t+1}

    // ---- all 8 gate tiles + MLP from h_{t-1}, x_t (independent: deep ILP)
    const f16x8 Bz = mk8(q == 0 ? pk16(xv.x, xv.y) : zz,
                         q == 0 ? pk16(xv.z, xv.w) : zz, zz, zz);
    f32x4 D[8];
    #pragma unroll
    for (int tl = 0; tl < 8; ++tl)
      D[tl] = mfma16(Aih[tl], Bz, mfma16(Ahh[tl], Bh, Cb[tl]));
    const f32x4 M0 = mfma16(Aw1[0], Bh, Cb1[0]);
    const f32x4 M1 = mfma16(Aw1[1], Bh, Cb1[1]);

    // ---- d_{t-1} = sigmoid(relu(M)*W2 + b2)  (hidden under gate activations)
    float y = 0.0f;
    #pragma unroll
    for (int r2 = 0; r2 < 4; ++r2) {
      y = fmaf(W2v[0][r2], fmaxf(M0[r2], 0.0f), y);
      y = fmaf(W2v[1][r2], fmaxf(M1[r2], 0.0f), y);
    }
    y += __builtin_bit_cast(float, __builtin_amdgcn_ds_swizzle(
             __builtin_bit_cast(int, y), 0x401F));      // xor-16 (q^1)
    y += __shfl_xor(y, 32);                             // q^2
    float dl = fsigmoid(y + b2s);
    dl = t ? dl : 0.0f;                                 // reference d_{-1} = 0
    if (q == 0 && t) orow[t - 1] = dl;

    // ---- activation per tile (d post-add; Wd is keT-scaled like D)
    f32x4 Ac[8];
    #pragma unroll
    for (int tl = 0; tl < 8; ++tl) {
      #pragma unroll
      for (int r2 = 0; r2 < 4; ++r2) {
        const float dd = fmaf(Wd[tl][r2], dl, D[tl][r2]);
        const float rc = __builtin_amdgcn_rcpf(1.0f + ex2(dd));
        Ac[tl][r2] = (tl == 4 || tl == 5) ? fmaf(2.0f, rc, -1.0f) : rc;
      }
    }

    // ---- lane-local c/h update: s<4 -> even tiles (hid 4q+s),
    //      s>=4 -> odd tiles (hid 16+4q+(s-4))
    float hN[8];
    #pragma unroll
    for (int s = 0; s < 8; ++s) {
      const int odd = s >> 2, r2 = s & 3;
      const float iv = Ac[0 + odd][r2];
      const float fv = Ac[2 + odd][r2];
      const float gv = Ac[4 + odd][r2];
      const float ov = Ac[6 + odd][r2];
      const float cc = fmaf(fv, cst[s], iv * gv);
      cst[s] = cc;
      const float tc = fmaf(2.0f,
          __builtin_amdgcn_rcpf(1.0f + ex2(-2.0f * LOG2E * cc)), -1.0f);
      hN[s] = ov * tc;
    }
    // Bh slot j (j<4): h[4q+j] = hN[j]; (j>=4): h[16+4q+(j-4)] = hN[j]  ✓
    Bh = mk8(pk16(hN[0], hN[1]), pk16(hN[2], hN[3]),
             pk16(hN[4], hN[5]), pk16(hN[6], hN[7]));
    xv = xn;
  }

  // ---- epilogue: d_{T-1} from h_{T-1}
  const f32x4 M0 = mfma16(Aw1[0], Bh, Cb1[0]);
  const f32x4 M1 = mfma16(Aw1[1], Bh, Cb1[1]);
  float y = 0.0f;
  #pragma unroll
  for (int r2 = 0; r2 < 4; ++r2) {
    y = fmaf(W2v[0][r2], fmaxf(M0[r2], 0.0f), y);
    y = fmaf(W2v[1][r2], fmaxf(M1[r2], 0.0f), y);
  }
  y += __builtin_bit_cast(float, __builtin_amdgcn_ds_swizzle(
           __builtin_bit_cast(int, y), 0x401F));
  y += __shfl_xor(y, 32);
  const float dl = fsigmoid(y + b2s);
  if (q == 0) orow[T_STEPS - 1] = dl;
}

extern "C" void kernel_launch(void* const* d_in, const int* in_sizes, int n_in,
                              void* d_out, int out_size, void* d_ws, size_t ws_size,
                              hipStream_t stream) {
  const float* x    = (const float*)d_in[0];
  const float* bn_g = (const float*)d_in[1];
  const float* bn_b = (const float*)d_in[2];
  const float* bn_m = (const float*)d_in[3];
  const float* bn_v = (const float*)d_in[4];
  const float* W_ih = (const float*)d_in[5];
  const float* b_ih = (const float*)d_in[6];
  const float* W_hh = (const float*)d_in[7];
  const float* b_hh = (const float*)d_in[8];
  const float* W1   = (const float*)d_in[9];
  const float* b1   = (const float*)d_in[10];
  const float* W2   = (const float*)d_in[11];
  const float* b2   = (const float*)d_in[12];
  float* out = (float*)d_out;

  const int B = in_sizes[0] / (T_STEPS * NF);   // 8192
  const int grid = B / 16;                      // one 64-thread wave per 16 rows

  hipLaunchKernelGGL(hedge_kernel, dim3(grid), dim3(64), 0, stream,
                     x, bn_g, bn_b, bn_m, bn_v, W_ih, b_ih, W_hh, b_hh,
                     W1, b1, W2, b2, out);
}